// Round 12
// baseline (1240.221 us; speedup 1.0000x reference)
//
#include <hip/hip_runtime.h>
#include <hip/hip_bf16.h>
#include <stdint.h>
#include <stddef.h>

#define T_LEN   2048
#define C_IN_   512
#define D_MODEL_ 1024
#define B_SZ    32

typedef __hip_bfloat16 bf16;
typedef __attribute__((ext_vector_type(8))) short short8;
typedef __attribute__((ext_vector_type(4))) float f32x4;

// ---------------------------------------------------------------------------
// async global->LDS, 16B per lane (linear dest: wave-uniform base + lane*16)
// ---------------------------------------------------------------------------
__device__ __forceinline__ void gload16(const void* g, void* l) {
    __builtin_amdgcn_global_load_lds(
        (const __attribute__((address_space(1))) uint32_t*)g,
        (__attribute__((address_space(3))) uint32_t*)l, 16, 0, 0);
}

// ---------------------------------------------------------------------------
// Kernel 1: W (fp32 [1024][512]) -> bf16, same layout
// ---------------------------------------------------------------------------
__global__ void wconv_kernel(const float* __restrict__ W, bf16* __restrict__ Wb) {
    int i = blockIdx.x * 256 + threadIdx.x;       // 131072 float4 units
    float4 v = ((const float4*)W)[i];
    bf16* o = Wb + (size_t)i * 4;
    o[0] = __float2bfloat16(v.x);
    o[1] = __float2bfloat16(v.y);
    o[2] = __float2bfloat16(v.z);
    o[3] = __float2bfloat16(v.w);
}

// ---------------------------------------------------------------------------
// Kernel 2: bidirectional EWMA — R12 MEASUREMENT: R6 body repeated 5x inside
// one dispatch (idempotent) so the dispatch (~200+ us) surfaces past the
// harness's ~155 us fills in rocprof top-5 and we finally see its counters.
// ---------------------------------------------------------------------------
__global__ __launch_bounds__(512)
void ewma_kernel(const float* __restrict__ x, bf16* __restrict__ A) {
    const int tid  = threadIdx.x;
    const int wid  = tid >> 6;          // 0..7
    const int lane = tid & 63;
    const int half = lane >> 5;         // 0,1 -> which row of the wave
    const int j    = lane & 31;         // chunk (64 t's each)
    const int b    = blockIdx.x >> 5;   // 0..31
    const int cg   = blockIdx.x & 31;   // 0..31 (16 channels per block)
    const int c_local = (wid << 1) | half;       // 0..15

    const float AL = 0.1f, OM = 0.9f;
    const float Q  = 1.179018457773862e-3f;      // 0.9^64

    __shared__ float buf[8 * 2048];              // 64KB: 8 rows x 8KB
    __shared__ bf16  stg[32 * 16 * 16];          // 16KB output stage

    const size_t xbase = ((size_t)b * C_IN_ + (cg << 4)) * T_LEN;
    const int srcu = tid ^ ((tid >> 4) & 7);     // involution on 16B units

    #pragma unroll 1
    for (int rep = 0; rep < 5; ++rep) {
        float xr[64];

        // ---- P1: two halves of 8 channel-rows through LDS
        #pragma unroll
        for (int h = 0; h < 2; ++h) {
            #pragma unroll
            for (int it = 0; it < 8; ++it)
                gload16(x + xbase + (size_t)(h * 8 + it) * T_LEN + srcu * 4,
                        (char*)buf + it * 8192 + tid * 16);
            asm volatile("s_waitcnt vmcnt(0)" ::: "memory");
            __syncthreads();
            if ((c_local >> 3) == h) {
                const char* rbase = (const char*)buf + (c_local & 7) * 8192;
                #pragma unroll
                for (int i = 0; i < 16; ++i) {
                    int p = (j * 16 + i) ^ (j & 7);
                    float4 v = *(const float4*)(rbase + p * 16);
                    xr[4*i+0] = v.x; xr[4*i+1] = v.y;
                    xr[4*i+2] = v.z; xr[4*i+3] = v.w;
                }
            }
            __syncthreads();                      // pulls drained before reuse
        }

        // ---- P2: local fwd scan
        float g = (j == 0) ? xr[0] : AL * xr[0];
        #pragma unroll
        for (int i = 1; i < 64; ++i) g = fmaf(OM, g, AL * xr[i]);

        // ---- P3: Kogge-Stone carry scan
        float F = g, coef = Q;
        #pragma unroll
        for (int d = 1; d < 32; d <<= 1) {
            float up = __shfl_up(F, d, 32);
            F += (j >= d) ? coef * up : 0.0f;
            coef *= coef;
        }
        float carry = __shfl_up(F, 1, 32);
        if (j == 0) carry = 0.0f;

        // ---- P4: seeded fwd recompute
        xr[0] = (j == 0) ? xr[0] : fmaf(OM, carry, AL * xr[0]);
        #pragma unroll
        for (int i = 1; i < 64; ++i) xr[i] = fmaf(OM, xr[i-1], AL * xr[i]);

        // ---- P5: local bwd scan from f
        float h2;
        {
            float incL = xr[63] - OM * xr[62];
            if (j == 31) incL *= 10.0f;
            h2 = incL;
            #pragma unroll
            for (int i = 62; i >= 1; --i) h2 = fmaf(OM, h2, xr[i] - OM * xr[i-1]);
            float inc0 = (j == 0) ? AL * xr[0] : (xr[0] - OM * carry);
            h2 = fmaf(OM, h2, inc0);
        }

        // ---- P6: bwd carry scan
        float Bv = h2; coef = Q;
        #pragma unroll
        for (int d = 1; d < 32; d <<= 1) {
            float dn = __shfl_down(Bv, d, 32);
            Bv += (j < 32 - d) ? coef * dn : 0.0f;
            coef *= coef;
        }
        float bnext = __shfl_down(Bv, 1, 32);
        if (j == 31) bnext = 0.0f;

        // ---- P7: final bwd recompute + combine
        {
            float bp = bnext;
            float incL = xr[63] - OM * xr[62];
            if (j == 31) incL *= 10.0f;
            float bb = fmaf(OM, bp, incL);
            xr[63] = 0.5f * (xr[63] + bb);
            bp = bb;
            #pragma unroll
            for (int i = 62; i >= 1; --i) {
                float inc = xr[i] - OM * xr[i-1];
                bb = fmaf(OM, bp, inc);
                xr[i] = 0.5f * (xr[i] + bb);
                bp = bb;
            }
            float inc0 = (j == 0) ? AL * xr[0] : (xr[0] - OM * carry);
            bb = fmaf(OM, bp, inc0);
            xr[0] = 0.5f * (xr[0] + bb);
        }

        // ---- P8: LDS transpose stage -> coalesced bf16 writes
        const size_t outbase = (size_t)(b * T_LEN) * C_IN_ + (cg << 4);
        #pragma unroll
        for (int grp = 0; grp < 4; ++grp) {
            __syncthreads();
            #pragma unroll
            for (int ii = 0; ii < 16; ++ii) {
                int elem = ((j * 16 + ii) * 16 + c_local) ^ ((j & 7) << 3);
                stg[elem] = __float2bfloat16(xr[grp * 16 + ii]);
            }
            __syncthreads();
            #pragma unroll
            for (int r = 0; r < 2; ++r) {
                int u   = tid * 2 + r;           // 1024 16B-units
                int jj  = u >> 5;
                int ii  = (u >> 1) & 15;
                int hf  = u & 1;
                int elem = ((jj * 16 + ii) * 16 + hf * 8) ^ ((jj & 7) << 3);
                float4 v = *(const float4*)&stg[elem];
                int t = jj * 64 + grp * 16 + ii;
                *(float4*)(A + outbase + (size_t)t * C_IN_ + hf * 8) = v;
            }
        }
    }
}

// ---------------------------------------------------------------------------
// Kernel 3: GEMM — R12 MEASUREMENT: R11 structure byte-identical, whole
// tile computation run TWICE inside one dispatch (idempotent d_out rewrite)
// so the dispatch (~240 us) surfaces in rocprof top-5 with full counters.
// ---------------------------------------------------------------------------
#define MFMA(a, b, c) __builtin_amdgcn_mfma_f32_16x16x32_bf16(a, b, c, 0, 0, 0)

__global__ __launch_bounds__(256, 4)
void gemm_kernel(const bf16* __restrict__ Amat, const bf16* __restrict__ Wb,
                 const float* __restrict__ bias, float* __restrict__ out) {
    constexpr int K = C_IN_, N = D_MODEL_;
    extern __shared__ bf16 lds[];                // 2 sets x (A 8KB + B 8KB)
    const int tid  = threadIdx.x;
    const int wid  = tid >> 6, lane = tid & 63;
    const int wr   = wid >> 1, wc = wid & 1;     // 2x2 wave grid, wave 64x64
    const int lr   = lane & 15;
    const int lg   = lane >> 4;

    int bid = blockIdx.x;
    int swz = (bid & 7) * 512 + (bid >> 3);
    const int mb = swz >> 3, nb = swz & 7;       // 512 x 8
    const int m0 = mb * 128, n0 = nb * 128;

    auto Abase = [&](int s) -> bf16* { return lds + s * 8192; };
    auto Bbase = [&](int s) -> bf16* { return lds + s * 8192 + 4096; };

    auto stage = [&](int kt, int s) {
        bf16* la = Abase(s);
        #pragma unroll
        for (int r = 0; r < 2; ++r) {
            int q = tid + r * 256;
            int row = q >> 2, u = q & 3;
            gload16(Amat + (size_t)(m0 + row) * K + kt * 32 + ((u ^ ((row >> 1) & 3)) << 3),
                    (char*)la + q * 16);
        }
        bf16* lb = Bbase(s);
        #pragma unroll
        for (int r = 0; r < 2; ++r) {
            int q = tid + r * 256;
            int row = q >> 2, u = q & 3;
            gload16(Wb + (size_t)(n0 + row) * K + kt * 32 + ((u ^ ((row >> 1) & 3)) << 3),
                    (char*)lb + q * 16);
        }
    };
    auto rdA = [&](int s, int f) -> short8 {
        int row = wr * 64 + f * 16 + lr;
        return *(const short8*)((const char*)Abase(s)
                                + row * 64 + ((lg ^ ((row >> 1) & 3)) << 4));
    };
    auto rdB = [&](int s, int n) -> short8 {
        int row = wc * 64 + n * 16 + lr;
        return *(const short8*)((const char*)Bbase(s)
                                + row * 64 + ((lg ^ ((row >> 1) & 3)) << 4));
    };

    #pragma unroll 1
    for (int pass = 0; pass < 2; ++pass) {
        f32x4 acc[4][4];
        #pragma unroll
        for (int f = 0; f < 4; ++f)
            #pragma unroll
            for (int n = 0; n < 4; ++n) acc[f][n] = (f32x4){0.f, 0.f, 0.f, 0.f};

        // prologue: kt0 -> set0, kt1 -> set1; drain kt0 (leave kt1's 4)
        // (vmcnt also counts pass-1 epilogue stores: waiting on <=4 is
        //  conservative-safe — the 4 newest ops are kt1's loads)
        stage(0, 0);
        stage(1, 1);
        asm volatile("s_waitcnt vmcnt(4)" ::: "memory");
        __builtin_amdgcn_s_barrier();

        #pragma unroll
        for (int kt = 0; kt < 16; ++kt) {
            const int s = kt & 1;
            short8 a[4], b[4];
            #pragma unroll
            for (int f = 0; f < 4; ++f) a[f] = rdA(s, f);
            #pragma unroll
            for (int n = 0; n < 4; ++n) b[n] = rdB(s, n);
            asm volatile("s_waitcnt lgkmcnt(0)");
            __builtin_amdgcn_sched_barrier(0);
            __builtin_amdgcn_s_barrier();        // all reads of set s landed

            if (kt < 14) stage(kt + 2, s);       // overwrite just-freed set s

            __builtin_amdgcn_s_setprio(1);
            #pragma unroll
            for (int f = 0; f < 4; ++f)
                #pragma unroll
                for (int n = 0; n < 4; ++n)
                    acc[f][n] = MFMA(a[f], b[n], acc[f][n]);
            __builtin_amdgcn_s_setprio(0);

            if (kt < 14)       asm volatile("s_waitcnt vmcnt(4)" ::: "memory");
            else if (kt == 14) asm volatile("s_waitcnt vmcnt(0)" ::: "memory");
            __builtin_amdgcn_s_barrier();        // set s^1 ready for next kt
        }

        // epilogue: C write + bias (fp32)
        const int crow = lg << 2;
        #pragma unroll
        for (int n = 0; n < 4; ++n) {
            int col = n0 + wc * 64 + n * 16 + lr;
            float bv = bias[col];
            #pragma unroll
            for (int f = 0; f < 4; ++f) {
                size_t rbase = (size_t)(m0 + wr * 64 + f * 16 + crow) * N + col;
                #pragma unroll
                for (int r = 0; r < 4; ++r)
                    out[rbase + (size_t)r * N] = acc[f][n][r] + bv;
            }
        }
    }
}

// ---------------------------------------------------------------------------
extern "C" void kernel_launch(void* const* d_in, const int* in_sizes, int n_in,
                              void* d_out, int out_size, void* d_ws, size_t ws_size,
                              hipStream_t stream) {
    const float* x    = (const float*)d_in[0];
    const float* W    = (const float*)d_in[1];
    const float* bias = (const float*)d_in[2];
    float* out = (float*)d_out;

    bf16* Wb   = (bf16*)d_ws;                          // 1MB
    bf16* Amat = (bf16*)((char*)d_ws + (1 << 21));     // 64MB at +2MB

    hipLaunchKernelGGL(wconv_kernel, dim3(512), dim3(256), 0, stream, W, Wb);
    hipLaunchKernelGGL(ewma_kernel, dim3(B_SZ * 32), dim3(512), 0, stream, x, Amat);
    hipLaunchKernelGGL(gemm_kernel,
                       dim3((B_SZ * T_LEN / 128) * (D_MODEL_ / 128)),
                       dim3(256), 32768, stream, Amat, Wb, bias, out);
}

// Round 13
// 643.385 us; speedup vs baseline: 1.9276x; 1.9276x over previous
//
#include <hip/hip_runtime.h>
#include <hip/hip_bf16.h>
#include <stdint.h>
#include <stddef.h>

#define T_LEN   2048
#define C_IN_   512
#define D_MODEL_ 1024
#define B_SZ    32

typedef __hip_bfloat16 bf16;
typedef __attribute__((ext_vector_type(8))) short short8;
typedef __attribute__((ext_vector_type(4))) float f32x4;

// ---------------------------------------------------------------------------
// async global->LDS, 16B per lane (used by EWMA staging only)
// ---------------------------------------------------------------------------
__device__ __forceinline__ void gload16(const void* g, void* l) {
    __builtin_amdgcn_global_load_lds(
        (const __attribute__((address_space(1))) uint32_t*)g,
        (__attribute__((address_space(3))) uint32_t*)l, 16, 0, 0);
}

// ---------------------------------------------------------------------------
// Kernel 1: W (fp32 [1024][512]) -> bf16, same layout
// ---------------------------------------------------------------------------
__global__ void wconv_kernel(const float* __restrict__ W, bf16* __restrict__ Wb) {
    int i = blockIdx.x * 256 + threadIdx.x;       // 131072 float4 units
    float4 v = ((const float4*)W)[i];
    bf16* o = Wb + (size_t)i * 4;
    o[0] = __float2bfloat16(v.x);
    o[1] = __float2bfloat16(v.y);
    o[2] = __float2bfloat16(v.z);
    o[3] = __float2bfloat16(v.w);
}

// ---------------------------------------------------------------------------
// Kernel 2: bidirectional EWMA (byte-identical to R6 — frozen control)
// ---------------------------------------------------------------------------
__global__ __launch_bounds__(512)
void ewma_kernel(const float* __restrict__ x, bf16* __restrict__ A) {
    const int tid  = threadIdx.x;
    const int wid  = tid >> 6;          // 0..7
    const int lane = tid & 63;
    const int half = lane >> 5;         // 0,1 -> which row of the wave
    const int j    = lane & 31;         // chunk (64 t's each)
    const int b    = blockIdx.x >> 5;   // 0..31
    const int cg   = blockIdx.x & 31;   // 0..31 (16 channels per block)
    const int c_local = (wid << 1) | half;       // 0..15

    const float AL = 0.1f, OM = 0.9f;
    const float Q  = 1.179018457773862e-3f;      // 0.9^64

    __shared__ float buf[8 * 2048];              // 64KB: 8 rows x 8KB
    __shared__ bf16  stg[32 * 16 * 16];          // 16KB output stage

    float xr[64];
    const size_t xbase = ((size_t)b * C_IN_ + (cg << 4)) * T_LEN;
    const int srcu = tid ^ ((tid >> 4) & 7);     // involution on 16B units

    // ---- P1: two halves of 8 channel-rows through LDS
    #pragma unroll
    for (int h = 0; h < 2; ++h) {
        #pragma unroll
        for (int it = 0; it < 8; ++it)
            gload16(x + xbase + (size_t)(h * 8 + it) * T_LEN + srcu * 4,
                    (char*)buf + it * 8192 + tid * 16);
        asm volatile("s_waitcnt vmcnt(0)" ::: "memory");
        __syncthreads();
        if ((c_local >> 3) == h) {
            const char* rbase = (const char*)buf + (c_local & 7) * 8192;
            #pragma unroll
            for (int i = 0; i < 16; ++i) {
                int p = (j * 16 + i) ^ (j & 7);
                float4 v = *(const float4*)(rbase + p * 16);
                xr[4*i+0] = v.x; xr[4*i+1] = v.y;
                xr[4*i+2] = v.z; xr[4*i+3] = v.w;
            }
        }
        __syncthreads();                          // pulls drained before reuse
    }

    // ---- P2: local fwd scan
    float g = (j == 0) ? xr[0] : AL * xr[0];
    #pragma unroll
    for (int i = 1; i < 64; ++i) g = fmaf(OM, g, AL * xr[i]);

    // ---- P3: Kogge-Stone carry scan
    float F = g, coef = Q;
    #pragma unroll
    for (int d = 1; d < 32; d <<= 1) {
        float up = __shfl_up(F, d, 32);
        F += (j >= d) ? coef * up : 0.0f;
        coef *= coef;
    }
    float carry = __shfl_up(F, 1, 32);
    if (j == 0) carry = 0.0f;

    // ---- P4: seeded fwd recompute
    xr[0] = (j == 0) ? xr[0] : fmaf(OM, carry, AL * xr[0]);
    #pragma unroll
    for (int i = 1; i < 64; ++i) xr[i] = fmaf(OM, xr[i-1], AL * xr[i]);

    // ---- P5: local bwd scan from f
    float h2;
    {
        float incL = xr[63] - OM * xr[62];
        if (j == 31) incL *= 10.0f;
        h2 = incL;
        #pragma unroll
        for (int i = 62; i >= 1; --i) h2 = fmaf(OM, h2, xr[i] - OM * xr[i-1]);
        float inc0 = (j == 0) ? AL * xr[0] : (xr[0] - OM * carry);
        h2 = fmaf(OM, h2, inc0);
    }

    // ---- P6: bwd carry scan
    float Bv = h2; coef = Q;
    #pragma unroll
    for (int d = 1; d < 32; d <<= 1) {
        float dn = __shfl_down(Bv, d, 32);
        Bv += (j < 32 - d) ? coef * dn : 0.0f;
        coef *= coef;
    }
    float bnext = __shfl_down(Bv, 1, 32);
    if (j == 31) bnext = 0.0f;

    // ---- P7: final bwd recompute + combine
    {
        float bp = bnext;
        float incL = xr[63] - OM * xr[62];
        if (j == 31) incL *= 10.0f;
        float bb = fmaf(OM, bp, incL);
        xr[63] = 0.5f * (xr[63] + bb);
        bp = bb;
        #pragma unroll
        for (int i = 62; i >= 1; --i) {
            float inc = xr[i] - OM * xr[i-1];
            bb = fmaf(OM, bp, inc);
            xr[i] = 0.5f * (xr[i] + bb);
            bp = bb;
        }
        float inc0 = (j == 0) ? AL * xr[0] : (xr[0] - OM * carry);
        bb = fmaf(OM, bp, inc0);
        xr[0] = 0.5f * (xr[0] + bb);
    }

    // ---- P8: LDS transpose stage -> coalesced bf16 writes
    const size_t outbase = (size_t)(b * T_LEN) * C_IN_ + (cg << 4);
    #pragma unroll
    for (int grp = 0; grp < 4; ++grp) {
        __syncthreads();
        #pragma unroll
        for (int ii = 0; ii < 16; ++ii) {
            int elem = ((j * 16 + ii) * 16 + c_local) ^ ((j & 7) << 3);
            stg[elem] = __float2bfloat16(xr[grp * 16 + ii]);
        }
        __syncthreads();
        #pragma unroll
        for (int r = 0; r < 2; ++r) {
            int u   = tid * 2 + r;               // 1024 16B-units
            int jj  = u >> 5;
            int ii  = (u >> 1) & 15;
            int hf  = u & 1;
            int elem = ((jj * 16 + ii) * 16 + hf * 8) ^ ((jj & 7) << 3);
            float4 v = *(const float4*)&stg[elem];
            int t = jj * 64 + grp * 16 + ii;
            *(float4*)(A + outbase + (size_t)t * C_IN_ + hf * 8) = v;
        }
    }
}

// ---------------------------------------------------------------------------
// Kernel 3: GEMM  out[m][n] = sum_k A[m][k]*W[n][k] + bias[n]
// R13: R4's exact geometry (256x128, BK=32, 4 waves, 2-barrier loop) with
// REG-STAGING instead of global_load_lds: global_load_dwordx4 -> VGPR ->
// swizzled ds_write_b128 (HipKittens' staging). Tests + fixes the theory
// that gload_lds misses L3: R10's normal-load kernel fetched A once
// (65 MB), while every gload_lds variant's 120us matches a full 537MB
// A-refetch. Depth-1 pipeline: gld(kt+2) issued under kt's MFMA; consumed
// at kt+1 after vmcnt(0). LDS 2x24KB=48KB -> 3 blocks/CU, 12 waves/CU.
// ---------------------------------------------------------------------------
#define MFMA(a, b, c) __builtin_amdgcn_mfma_f32_16x16x32_bf16(a, b, c, 0, 0, 0)

__global__ __launch_bounds__(256, 3)
void gemm_kernel(const bf16* __restrict__ Amat, const bf16* __restrict__ Wb,
                 const float* __restrict__ bias, float* __restrict__ out) {
    constexpr int K = C_IN_, N = D_MODEL_;
    extern __shared__ bf16 lds[];                // 2 sets x (A 16KB + B 8KB)
    const int tid  = threadIdx.x;
    const int w    = tid >> 6, lane = tid & 63;
    const int lr   = lane & 15;
    const int lg   = lane >> 4;

    // T1: bijective XCD swizzle (2048 blocks); 8 nb share each A panel
    int bid = blockIdx.x;
    int swz = (bid & 7) * 256 + (bid >> 3);
    const int mb = swz >> 3, nb = swz & 7;
    const int m0 = mb * 256, n0 = nb * 128;

    auto Abase = [&](int s) -> bf16* { return lds + s * 12288; };          // 16KB
    auto Bbase = [&](int s) -> bf16* { return lds + s * 12288 + 8192; };   // 8KB

    // load one K-tile (A 256x32 + B 128x32) into 6 short8 regs (coalesced)
    auto gld = [&](int kt, short8 r[6]) {
        #pragma unroll
        for (int i = 0; i < 4; ++i) {
            int q = tid + i * 256, row = q >> 2, u = q & 3;
            r[i] = *(const short8*)(Amat + (size_t)(m0 + row) * K + kt * 32 + u * 8);
        }
        #pragma unroll
        for (int i = 0; i < 2; ++i) {
            int q = tid + i * 256, row = q >> 2, u = q & 3;
            r[4 + i] = *(const short8*)(Wb + (size_t)(n0 + row) * K + kt * 32 + u * 8);
        }
    };
    // swizzled ds_write of the staged regs (swizzle matches rdA/rdB)
    auto sst = [&](int s, short8 r[6]) {
        bf16* la = Abase(s); bf16* lb = Bbase(s);
        #pragma unroll
        for (int i = 0; i < 4; ++i) {
            int q = tid + i * 256, row = q >> 2, u = q & 3;
            *(short8*)((char*)la + row * 64 + ((u ^ ((row >> 1) & 3)) << 4)) = r[i];
        }
        #pragma unroll
        for (int i = 0; i < 2; ++i) {
            int q = tid + i * 256, row = q >> 2, u = q & 3;
            *(short8*)((char*)lb + row * 64 + ((u ^ ((row >> 1) & 3)) << 4)) = r[4 + i];
        }
    };
    auto rdA = [&](int s, int f) -> short8 {
        int row = w * 64 + f * 16 + lr;
        return *(const short8*)((const char*)Abase(s)
                                + row * 64 + ((lg ^ ((row >> 1) & 3)) << 4));
    };
    auto rdB = [&](int s, int n) -> short8 {
        int row = n * 16 + lr;
        return *(const short8*)((const char*)Bbase(s)
                                + row * 64 + ((lg ^ ((row >> 1) & 3)) << 4));
    };

    f32x4 acc[4][8];
    #pragma unroll
    for (int f = 0; f < 4; ++f)
        #pragma unroll
        for (int n = 0; n < 8; ++n) acc[f][n] = (f32x4){0.f, 0.f, 0.f, 0.f};

    // ---- prologue: kt0 -> set0 (via regs), kt1 loads in flight
    short8 r[6];
    gld(0, r);
    asm volatile("s_waitcnt vmcnt(0)" ::: "memory");
    sst(0, r);
    gld(1, r);                                    // in flight across barrier
    asm volatile("s_waitcnt lgkmcnt(0)");
    __builtin_amdgcn_s_barrier();

    // ---- K loop: 16 K-tiles of 32
    #pragma unroll
    for (int kt = 0; kt < 16; ++kt) {
        const int s = kt & 1;
        short8 a[4], b[8];
        #pragma unroll
        for (int f = 0; f < 4; ++f) a[f] = rdA(s, f);
        #pragma unroll
        for (int n = 0; n < 8; ++n) b[n] = rdB(s, n);
        if (kt < 15) {                            // write kt+1 into freed set
            asm volatile("s_waitcnt vmcnt(0)" ::: "memory");
            sst(s ^ 1, r);
        }
        asm volatile("s_waitcnt lgkmcnt(0)");     // a,b ready; writes drained
        __builtin_amdgcn_sched_barrier(0);
        if (kt < 14) gld(kt + 2, r);              // issue under MFMA phase

        __builtin_amdgcn_s_setprio(1);
        #pragma unroll
        for (int f = 0; f < 4; ++f)
            #pragma unroll
            for (int n = 0; n < 8; ++n)
                acc[f][n] = MFMA(a[f], b[n], acc[f][n]);
        __builtin_amdgcn_s_setprio(0);
        __builtin_amdgcn_s_barrier();             // set s^1 ready for kt+1
    }

    // ---- epilogue: C write + bias (fp32)
    const int crow = lg << 2;
    #pragma unroll
    for (int n = 0; n < 8; ++n) {
        int col = n0 + n * 16 + lr;
        float bv = bias[col];
        #pragma unroll
        for (int f = 0; f < 4; ++f) {
            size_t rbase = (size_t)(m0 + w * 64 + f * 16 + crow) * N + col;
            #pragma unroll
            for (int rr = 0; rr < 4; ++rr)
                out[rbase + (size_t)rr * N] = acc[f][n][rr] + bv;
        }
    }
}

// ---------------------------------------------------------------------------
extern "C" void kernel_launch(void* const* d_in, const int* in_sizes, int n_in,
                              void* d_out, int out_size, void* d_ws, size_t ws_size,
                              hipStream_t stream) {
    const float* x    = (const float*)d_in[0];
    const float* W    = (const float*)d_in[1];
    const float* bias = (const float*)d_in[2];
    float* out = (float*)d_out;

    bf16* Wb   = (bf16*)d_ws;                          // 1MB
    bf16* Amat = (bf16*)((char*)d_ws + (1 << 21));     // 64MB at +2MB

    hipLaunchKernelGGL(wconv_kernel, dim3(512), dim3(256), 0, stream, W, Wb);
    hipLaunchKernelGGL(ewma_kernel, dim3(B_SZ * 32), dim3(512), 0, stream, x, Amat);
    hipLaunchKernelGGL(gemm_kernel,
                       dim3((B_SZ * T_LEN / 256) * (D_MODEL_ / 128)),
                       dim3(256), 49152, stream, Amat, Wb, bias, out);
}

// Round 14
// 175.783 us; speedup vs baseline: 7.0554x; 3.6601x over previous
//
#include <hip/hip_runtime.h>
#include <hip/hip_bf16.h>
#include <stdint.h>
#include <stddef.h>

#define T_LEN   2048
#define C_IN_   512
#define D_MODEL_ 1024
#define B_SZ    32

typedef __hip_bfloat16 bf16;
typedef __attribute__((ext_vector_type(8))) short short8;
typedef __attribute__((ext_vector_type(4))) float f32x4;

// ---------------------------------------------------------------------------
// async global->LDS, 16B per lane (used by EWMA staging only)
// ---------------------------------------------------------------------------
__device__ __forceinline__ void gload16(const void* g, void* l) {
    __builtin_amdgcn_global_load_lds(
        (const __attribute__((address_space(1))) uint32_t*)g,
        (__attribute__((address_space(3))) uint32_t*)l, 16, 0, 0);
}

// ---------------------------------------------------------------------------
// Kernel 1: W (fp32 [1024][512]) -> bf16, same layout
// ---------------------------------------------------------------------------
__global__ void wconv_kernel(const float* __restrict__ W, bf16* __restrict__ Wb) {
    int i = blockIdx.x * 256 + threadIdx.x;       // 131072 float4 units
    float4 v = ((const float4*)W)[i];
    bf16* o = Wb + (size_t)i * 4;
    o[0] = __float2bfloat16(v.x);
    o[1] = __float2bfloat16(v.y);
    o[2] = __float2bfloat16(v.z);
    o[3] = __float2bfloat16(v.w);
}

// ---------------------------------------------------------------------------
// Kernel 2: bidirectional EWMA (byte-identical to R6 — frozen control)
// ---------------------------------------------------------------------------
__global__ __launch_bounds__(512)
void ewma_kernel(const float* __restrict__ x, bf16* __restrict__ A) {
    const int tid  = threadIdx.x;
    const int wid  = tid >> 6;          // 0..7
    const int lane = tid & 63;
    const int half = lane >> 5;         // 0,1 -> which row of the wave
    const int j    = lane & 31;         // chunk (64 t's each)
    const int b    = blockIdx.x >> 5;   // 0..31
    const int cg   = blockIdx.x & 31;   // 0..31 (16 channels per block)
    const int c_local = (wid << 1) | half;       // 0..15

    const float AL = 0.1f, OM = 0.9f;
    const float Q  = 1.179018457773862e-3f;      // 0.9^64

    __shared__ float buf[8 * 2048];              // 64KB: 8 rows x 8KB
    __shared__ bf16  stg[32 * 16 * 16];          // 16KB output stage

    float xr[64];
    const size_t xbase = ((size_t)b * C_IN_ + (cg << 4)) * T_LEN;
    const int srcu = tid ^ ((tid >> 4) & 7);     // involution on 16B units

    // ---- P1: two halves of 8 channel-rows through LDS
    #pragma unroll
    for (int h = 0; h < 2; ++h) {
        #pragma unroll
        for (int it = 0; it < 8; ++it)
            gload16(x + xbase + (size_t)(h * 8 + it) * T_LEN + srcu * 4,
                    (char*)buf + it * 8192 + tid * 16);
        asm volatile("s_waitcnt vmcnt(0)" ::: "memory");
        __syncthreads();
        if ((c_local >> 3) == h) {
            const char* rbase = (const char*)buf + (c_local & 7) * 8192;
            #pragma unroll
            for (int i = 0; i < 16; ++i) {
                int p = (j * 16 + i) ^ (j & 7);
                float4 v = *(const float4*)(rbase + p * 16);
                xr[4*i+0] = v.x; xr[4*i+1] = v.y;
                xr[4*i+2] = v.z; xr[4*i+3] = v.w;
            }
        }
        __syncthreads();                          // pulls drained before reuse
    }

    // ---- P2: local fwd scan
    float g = (j == 0) ? xr[0] : AL * xr[0];
    #pragma unroll
    for (int i = 1; i < 64; ++i) g = fmaf(OM, g, AL * xr[i]);

    // ---- P3: Kogge-Stone carry scan
    float F = g, coef = Q;
    #pragma unroll
    for (int d = 1; d < 32; d <<= 1) {
        float up = __shfl_up(F, d, 32);
        F += (j >= d) ? coef * up : 0.0f;
        coef *= coef;
    }
    float carry = __shfl_up(F, 1, 32);
    if (j == 0) carry = 0.0f;

    // ---- P4: seeded fwd recompute
    xr[0] = (j == 0) ? xr[0] : fmaf(OM, carry, AL * xr[0]);
    #pragma unroll
    for (int i = 1; i < 64; ++i) xr[i] = fmaf(OM, xr[i-1], AL * xr[i]);

    // ---- P5: local bwd scan from f
    float h2;
    {
        float incL = xr[63] - OM * xr[62];
        if (j == 31) incL *= 10.0f;
        h2 = incL;
        #pragma unroll
        for (int i = 62; i >= 1; --i) h2 = fmaf(OM, h2, xr[i] - OM * xr[i-1]);
        float inc0 = (j == 0) ? AL * xr[0] : (xr[0] - OM * carry);
        h2 = fmaf(OM, h2, inc0);
    }

    // ---- P6: bwd carry scan
    float Bv = h2; coef = Q;
    #pragma unroll
    for (int d = 1; d < 32; d <<= 1) {
        float dn = __shfl_down(Bv, d, 32);
        Bv += (j < 32 - d) ? coef * dn : 0.0f;
        coef *= coef;
    }
    float bnext = __shfl_down(Bv, 1, 32);
    if (j == 31) bnext = 0.0f;

    // ---- P7: final bwd recompute + combine
    {
        float bp = bnext;
        float incL = xr[63] - OM * xr[62];
        if (j == 31) incL *= 10.0f;
        float bb = fmaf(OM, bp, incL);
        xr[63] = 0.5f * (xr[63] + bb);
        bp = bb;
        #pragma unroll
        for (int i = 62; i >= 1; --i) {
            float inc = xr[i] - OM * xr[i-1];
            bb = fmaf(OM, bp, inc);
            xr[i] = 0.5f * (xr[i] + bb);
            bp = bb;
        }
        float inc0 = (j == 0) ? AL * xr[0] : (xr[0] - OM * carry);
        bb = fmaf(OM, bp, inc0);
        xr[0] = 0.5f * (xr[0] + bb);
    }

    // ---- P8: LDS transpose stage -> coalesced bf16 writes
    const size_t outbase = (size_t)(b * T_LEN) * C_IN_ + (cg << 4);
    #pragma unroll
    for (int grp = 0; grp < 4; ++grp) {
        __syncthreads();
        #pragma unroll
        for (int ii = 0; ii < 16; ++ii) {
            int elem = ((j * 16 + ii) * 16 + c_local) ^ ((j & 7) << 3);
            stg[elem] = __float2bfloat16(xr[grp * 16 + ii]);
        }
        __syncthreads();
        #pragma unroll
        for (int r = 0; r < 2; ++r) {
            int u   = tid * 2 + r;               // 1024 16B-units
            int jj  = u >> 5;
            int ii  = (u >> 1) & 15;
            int hf  = u & 1;
            int elem = ((jj * 16 + ii) * 16 + hf * 8) ^ ((jj & 7) << 3);
            float4 v = *(const float4*)&stg[elem];
            int t = jj * 64 + grp * 16 + ii;
            *(float4*)(A + outbase + (size_t)t * C_IN_ + hf * 8) = v;
        }
    }
}

// ---------------------------------------------------------------------------
// Kernel 3: GEMM  out[m][n] = sum_k A[m][k]*W[n][k] + bias[n]
// R14: reg-staging retry, TRAP-FREE. R4 geometry (256x128, BK=32, 4 waves,
// one barrier per kt). Staging via SIX NAMED short8 regs (no arrays, no
// lambdas -> rule #20 safe) and __launch_bounds__(256,2) so the ~220-reg
// working set fits (R13 failed on (256,3)'s 170-reg cap + array params:
// VGPR=84, 1.9GB scratch). All addressing precomputed per-thread constants.
// Tests: does replacing global_load_lds with reg-staging (L1/L2/L3-cached
// loads, like R10's FETCH=65MB) kill the presumed 537MB A-refetch?
// ---------------------------------------------------------------------------
#define MFMA(a, b, c) __builtin_amdgcn_mfma_f32_16x16x32_bf16(a, b, c, 0, 0, 0)

__global__ __launch_bounds__(256, 2)
void gemm_kernel(const bf16* __restrict__ Amat, const bf16* __restrict__ Wb,
                 const float* __restrict__ bias, float* __restrict__ out) {
    constexpr int K = C_IN_, N = D_MODEL_;
    extern __shared__ bf16 lds[];                // 2 sets x (A 16KB + B 8KB)
    const int tid  = threadIdx.x;
    const int w    = tid >> 6, lane = tid & 63;
    const int lr   = lane & 15;
    const int lg   = lane >> 4;

    // T1: bijective XCD swizzle (2048 blocks); 8 nb share each A panel
    int bid = blockIdx.x;
    int swz = (bid & 7) * 256 + (bid >> 3);
    const int mb = swz >> 3, nb = swz & 7;
    const int m0 = mb * 256, n0 = nb * 128;

    // per-thread staging constants (all compile-time-shaped, no arrays)
    const int row0 = tid >> 2;                   // 0..63
    const int u    = tid & 3;                    // 16B unit within row
    const int sw   = u ^ ((tid >> 3) & 3);       // swizzled phys unit
    // global row bases
    const bf16* Ag0 = Amat + (size_t)(m0 + row0) * K + u * 8;
    const bf16* Bg0 = Wb   + (size_t)(n0 + row0) * K + u * 8;
    // LDS byte offsets (A rows row0+64i at 64B/row; B rows row0+64i)
    const int wA = row0 * 64 + (sw << 4);        // + i*4096
    const int wB = row0 * 64 + (sw << 4);        // + i*4096, B half

    f32x4 acc[4][8];
    #pragma unroll
    for (int f = 0; f < 4; ++f)
        #pragma unroll
        for (int n = 0; n < 8; ++n) acc[f][n] = (f32x4){0.f, 0.f, 0.f, 0.f};

    short8 r0, r1, r2, r3, r4, r5;

#define GLD(kt) do {                                                        \
        r0 = *(const short8*)(Ag0 + (size_t)  0 * K + (kt) * 32);           \
        r1 = *(const short8*)(Ag0 + (size_t) 64 * K + (kt) * 32);           \
        r2 = *(const short8*)(Ag0 + (size_t)128 * K + (kt) * 32);           \
        r3 = *(const short8*)(Ag0 + (size_t)192 * K + (kt) * 32);           \
        r4 = *(const short8*)(Bg0 + (size_t)  0 * K + (kt) * 32);           \
        r5 = *(const short8*)(Bg0 + (size_t) 64 * K + (kt) * 32);           \
    } while (0)

#define SST(s) do {                                                         \
        char* la = (char*)lds + (s) * 24576;                                \
        char* lb = la + 16384;                                              \
        *(short8*)(la + wA +     0) = r0;                                   \
        *(short8*)(la + wA +  4096) = r1;                                   \
        *(short8*)(la + wA +  8192) = r2;                                   \
        *(short8*)(la + wA + 12288) = r3;                                   \
        *(short8*)(lb + wB +     0) = r4;                                   \
        *(short8*)(lb + wB +  4096) = r5;                                   \
    } while (0)

    auto rdA = [&](int s, int f) -> short8 {
        int row = w * 64 + f * 16 + lr;
        return *(const short8*)((const char*)lds + s * 49152
                                + row * 64 + ((lg ^ ((row >> 1) & 3)) << 4));
    };
    auto rdB = [&](int s, int n) -> short8 {
        int row = n * 16 + lr;
        return *(const short8*)((const char*)lds + s * 49152 + 32768
                                + row * 64 + ((lg ^ ((row >> 1) & 3)) << 4));
    };
    // NOTE: lds layout: set s at byte s*24576; A 16KB then B 8KB. rdA/rdB
    // must match SST: set base = s*24576, B at +16384.
    // (rdA/rdB above use 49152/32768 — fix to 24576/16384.)

    auto rdA2 = [&](int s, int f) -> short8 {
        int row = w * 64 + f * 16 + lr;
        return *(const short8*)((const char*)lds + s * 24576
                                + row * 64 + ((lg ^ ((row >> 1) & 3)) << 4));
    };
    auto rdB2 = [&](int s, int n) -> short8 {
        int row = n * 16 + lr;
        return *(const short8*)((const char*)lds + s * 24576 + 16384
                                + row * 64 + ((lg ^ ((row >> 1) & 3)) << 4));
    };

    // ---- prologue: kt0 -> set0 via regs; kt1 loads left in flight
    GLD(0);
    asm volatile("s_waitcnt vmcnt(0)" ::: "memory");
    SST(0);
    GLD(1);
    asm volatile("s_waitcnt lgkmcnt(0)");
    __builtin_amdgcn_s_barrier();

    // ---- K loop: 16 K-tiles of 32; ONE barrier per kt
    #pragma unroll
    for (int kt = 0; kt < 16; ++kt) {
        const int s = kt & 1;
        short8 a0 = rdA2(s, 0), a1 = rdA2(s, 1), a2 = rdA2(s, 2), a3 = rdA2(s, 3);
        short8 b0 = rdB2(s, 0), b1 = rdB2(s, 1), b2 = rdB2(s, 2), b3 = rdB2(s, 3);
        short8 b4 = rdB2(s, 4), b5 = rdB2(s, 5), b6 = rdB2(s, 6), b7 = rdB2(s, 7);
        if (kt < 15) {
            asm volatile("s_waitcnt vmcnt(0)" ::: "memory");   // kt+1 regs in
            SST(s ^ 1);                                        // stage kt+1
        }
        asm volatile("s_waitcnt lgkmcnt(0)");   // frags ready, writes issued
        __builtin_amdgcn_sched_barrier(0);
        if (kt < 14) GLD(kt + 2);               // issue under MFMA

        __builtin_amdgcn_s_setprio(1);
        #pragma unroll
        for (int f = 0; f < 4; ++f) {
            short8 af = (f == 0) ? a0 : (f == 1) ? a1 : (f == 2) ? a2 : a3;
            acc[f][0] = MFMA(af, b0, acc[f][0]);
            acc[f][1] = MFMA(af, b1, acc[f][1]);
            acc[f][2] = MFMA(af, b2, acc[f][2]);
            acc[f][3] = MFMA(af, b3, acc[f][3]);
            acc[f][4] = MFMA(af, b4, acc[f][4]);
            acc[f][5] = MFMA(af, b5, acc[f][5]);
            acc[f][6] = MFMA(af, b6, acc[f][6]);
            acc[f][7] = MFMA(af, b7, acc[f][7]);
        }
        __builtin_amdgcn_s_setprio(0);
        __builtin_amdgcn_s_barrier();           // set s^1 ready for kt+1
    }
#undef GLD
#undef SST

    // ---- epilogue: C write + bias (fp32)
    const int crow = lg << 2;
    #pragma unroll
    for (int n = 0; n < 8; ++n) {
        int col = n0 + n * 16 + lr;
        float bv = bias[col];
        #pragma unroll
        for (int f = 0; f < 4; ++f) {
            size_t rbase = (size_t)(m0 + w * 64 + f * 16 + crow) * N + col;
            #pragma unroll
            for (int rr = 0; rr < 4; ++rr)
                out[rbase + (size_t)rr * N] = acc[f][n][rr] + bv;
        }
    }
    (void)rdA; (void)rdB;                        // silence unused (kept doc'd)
}

// ---------------------------------------------------------------------------
extern "C" void kernel_launch(void* const* d_in, const int* in_sizes, int n_in,
                              void* d_out, int out_size, void* d_ws, size_t ws_size,
                              hipStream_t stream) {
    const float* x    = (const float*)d_in[0];
    const float* W    = (const float*)d_in[1];
    const float* bias = (const float*)d_in[2];
    float* out = (float*)d_out;

    bf16* Wb   = (bf16*)d_ws;                          // 1MB
    bf16* Amat = (bf16*)((char*)d_ws + (1 << 21));     // 64MB at +2MB

    hipLaunchKernelGGL(wconv_kernel, dim3(512), dim3(256), 0, stream, W, Wb);
    hipLaunchKernelGGL(ewma_kernel, dim3(B_SZ * 32), dim3(512), 0, stream, x, Amat);
    hipLaunchKernelGGL(gemm_kernel,
                       dim3((B_SZ * T_LEN / 256) * (D_MODEL_ / 128)),
                       dim3(256), 49152, stream, Amat, Wb, bias, out);
}